// Round 1
// baseline (37.383 us; speedup 1.0000x reference)
//
#include <hip/hip_runtime.h>
#include <math.h>

#define PI_F 3.14159265358979323846f

// ---------------------------------------------------------------------------
// Kernel 1: one thread = one 2x2 patch = one 4-qubit circuit simulation.
// State: 16 complex amplitudes in registers (sr/si). All indices are
// compile-time constants so everything stays in VGPRs; CNOTs become register
// renames (zero instructions after copy propagation).
// Index convention: n = q0*8 + q1*4 + q2*2 + q3  (wire w <-> bit (3-w)).
// ---------------------------------------------------------------------------

// Apply a generic 2x2 complex gate on wire w.
#define GATE(w, U00R,U00I,U01R,U01I,U10R,U10I,U11R,U11I) do {                 \
    const int m_ = 1 << (3-(w));                                              \
    _Pragma("unroll")                                                         \
    for (int n0 = 0; n0 < 16; ++n0) {                                         \
      if (!(n0 & m_)) {                                                       \
        const int n1 = n0 | m_;                                               \
        const float ar = sr[n0], ai = si[n0];                                 \
        const float br = sr[n1], bi = si[n1];                                 \
        sr[n0] = (U00R)*ar - (U00I)*ai + (U01R)*br - (U01I)*bi;               \
        si[n0] = (U00R)*ai + (U00I)*ar + (U01R)*bi + (U01I)*br;               \
        sr[n1] = (U10R)*ar - (U10I)*ai + (U11R)*br - (U11I)*bi;               \
        si[n1] = (U10R)*ai + (U10I)*ar + (U11R)*bi + (U11I)*br;               \
      }                                                                       \
    }                                                                         \
  } while (0)

// CNOT(control c, target t): swap amplitudes with control bit = 1 across the
// target bit. Pure register permutation.
#define CNOT(c, t) do {                                                       \
    const int cm_ = 1 << (3-(c)), tm_ = 1 << (3-(t));                         \
    _Pragma("unroll")                                                         \
    for (int n = 0; n < 16; ++n) {                                            \
      if ((n & cm_) && !(n & tm_)) {                                          \
        const int n2 = n | tm_;                                               \
        const float tr_ = sr[n]; sr[n] = sr[n2]; sr[n2] = tr_;                \
        const float ti_ = si[n]; si[n] = si[n2]; si[n2] = ti_;                \
      }                                                                       \
    }                                                                         \
  } while (0)

#define CNOT_RING() do { CNOT(0,1); CNOT(1,2); CNOT(2,3); CNOT(3,0); } while (0)

// One scan step with group index g (compile-time constant): for each wire j,
// apply Rot U_g then the CNOT ring.
#define GROUPSTEP(g) do {                                                     \
    GATE(0, u00r[g],u00i[g],u01r[g],u01i[g],u10r[g],u10i[g],u11r[g],u11i[g]); \
    CNOT_RING();                                                              \
    GATE(1, u00r[g],u00i[g],u01r[g],u01i[g],u10r[g],u10i[g],u11r[g],u11i[g]); \
    CNOT_RING();                                                              \
    GATE(2, u00r[g],u00i[g],u01r[g],u01i[g],u10r[g],u10i[g],u11r[g],u11i[g]); \
    CNOT_RING();                                                              \
    GATE(3, u00r[g],u00i[g],u01r[g],u01i[g],u10r[g],u10i[g],u11r[g],u11i[g]); \
    CNOT_RING();                                                              \
  } while (0)

__global__ __launch_bounds__(64) void qcnn_circuit_kernel(
    const float* __restrict__ images,   // (64,1,28,28)
    const float* __restrict__ rp,       // (4,)
    float* __restrict__ qout)           // (64*196*4,)
{
  const int idx = blockIdx.x * 64 + threadIdx.x;
  if (idx >= 64 * 196) return;
  const int b  = idx / 196;
  const int pi = idx - b * 196;
  const int pj = pi / 14;
  const int pk = pi - pj * 14;

  const float* img = images + b * 784 + (2 * pj) * 28 + 2 * pk;
  float px[4];
  px[0] = img[0]  * PI_F;
  px[1] = img[1]  * PI_F;
  px[2] = img[28] * PI_F;
  px[3] = img[29] * PI_F;

  // 4 distinct Rot matrices (GROUP_IDX has period 4).
  // g%4: (phi,theta,omega) pixel indices = {0,1,2},{3,0,1},{2,3,0},{1,2,3}
  float u00r[4], u00i[4], u01r[4], u01i[4], u10r[4], u10i[4], u11r[4], u11i[4];
  {
    const int GIphi[4] = {0, 3, 2, 1};
    const int GIth [4] = {1, 0, 3, 2};
    const int GIom [4] = {2, 1, 0, 3};
#pragma unroll
    for (int g = 0; g < 4; ++g) {
      const float phi = px[GIphi[g]], th = px[GIth[g]], om = px[GIom[g]];
      float sa, ca; sincosf(0.5f * (phi + om), &sa, &ca);  // ep = ca - i*sa
      float sd, cd; sincosf(0.5f * (phi - om), &sd, &cd);  // em = cd + i*sd
      float st, ct; sincosf(0.5f * th, &st, &ct);
      u00r[g] =  ca * ct;  u00i[g] = -sa * ct;   //  ep * c
      u01r[g] = -cd * st;  u01i[g] = -sd * st;   // -em * s
      u10r[g] =  cd * st;  u10i[g] = -sd * st;   //  conj(em) * s
      u11r[g] =  ca * ct;  u11i[g] =  sa * ct;   //  conj(ep) * c
    }
  }

  float sr[16], si[16];
#pragma unroll
  for (int n = 0; n < 16; ++n) { sr[n] = 0.f; si[n] = 0.f; }
  sr[0] = 1.f;

  // 20 scan steps = 5 repetitions of the 4-group cycle. Keep the rep loop
  // rolled (#pragma unroll 1) so code size stays ~one cycle body; all state
  // indices inside are compile-time constants -> registers.
#pragma unroll 1
  for (int rep = 0; rep < 5; ++rep) {
    GROUPSTEP(0);
    GROUPSTEP(1);
    GROUPSTEP(2);
    GROUPSTEP(3);
  }

  // Deterministic stand-in for RandomLayers:
  // rx(p0)@w3, ry(p1)@w1, CNOT(0,2), rz(p2)@w0, rx(p3)@w2, CNOT(1,3)
  {
    float s0, c0; sincosf(0.5f * rp[0], &s0, &c0);
    GATE(3, c0, 0.f, 0.f, -s0, 0.f, -s0, c0, 0.f);          // RX
    float s1, c1; sincosf(0.5f * rp[1], &s1, &c1);
    GATE(1, c1, 0.f, -s1, 0.f, s1, 0.f, c1, 0.f);           // RY
    CNOT(0, 2);
    float s2, c2; sincosf(0.5f * rp[2], &s2, &c2);
    GATE(0, c2, -s2, 0.f, 0.f, 0.f, 0.f, c2, s2);           // RZ
    float s3, c3; sincosf(0.5f * rp[3], &s3, &c3);
    GATE(2, c3, 0.f, 0.f, -s3, 0.f, -s3, c3, 0.f);          // RX
    CNOT(1, 3);
  }

  // PauliZ expectation per wire: sum_n |a_n|^2 * (+1 if bit==0 else -1)
  float ev0 = 0.f, ev1 = 0.f, ev2 = 0.f, ev3 = 0.f;
#pragma unroll
  for (int n = 0; n < 16; ++n) {
    const float pn = sr[n] * sr[n] + si[n] * si[n];
    ev0 += (n & 8) ? -pn : pn;
    ev1 += (n & 4) ? -pn : pn;
    ev2 += (n & 2) ? -pn : pn;
    ev3 += (n & 1) ? -pn : pn;
  }

  float4 evv = make_float4(ev0, ev1, ev2, ev3);
  *reinterpret_cast<float4*>(qout + idx * 4) = evv;
}

// ---------------------------------------------------------------------------
// Kernel 2: FC (10x784) + log_softmax. One wave per image.
// ---------------------------------------------------------------------------
__global__ __launch_bounds__(64) void qcnn_fc_kernel(
    const float* __restrict__ q,     // (64,784)
    const float* __restrict__ fcw,   // (10,784)
    const float* __restrict__ fcb,   // (10,)
    float* __restrict__ out)         // (64,10)
{
  const int b    = blockIdx.x;
  const int lane = threadIdx.x;

  float acc[10];
#pragma unroll
  for (int o = 0; o < 10; ++o) acc[o] = 0.f;

  for (int i = lane; i < 784; i += 64) {
    const float qv = q[b * 784 + i];
#pragma unroll
    for (int o = 0; o < 10; ++o) acc[o] += qv * fcw[o * 784 + i];
  }

#pragma unroll
  for (int o = 0; o < 10; ++o) {
    for (int off = 32; off > 0; off >>= 1)
      acc[o] += __shfl_down(acc[o], off);
  }

  if (lane == 0) {
    float logits[10];
    float mx = -1e30f;
#pragma unroll
    for (int o = 0; o < 10; ++o) {
      logits[o] = acc[o] + fcb[o];
      mx = fmaxf(mx, logits[o]);
    }
    float se = 0.f;
#pragma unroll
    for (int o = 0; o < 10; ++o) se += expf(logits[o] - mx);
    const float lse = mx + logf(se);
#pragma unroll
    for (int o = 0; o < 10; ++o) out[b * 10 + o] = logits[o] - lse;
  }
}

// ---------------------------------------------------------------------------

extern "C" void kernel_launch(void* const* d_in, const int* in_sizes, int n_in,
                              void* d_out, int out_size, void* d_ws, size_t ws_size,
                              hipStream_t stream) {
  const float* images = (const float*)d_in[0];   // 64*1*28*28
  const float* rp     = (const float*)d_in[1];   // 4
  const float* fcw    = (const float*)d_in[2];   // 10*784
  const float* fcb    = (const float*)d_in[3];   // 10
  float* out = (float*)d_out;                    // 64*10
  float* q   = (float*)d_ws;                     // 64*196*4 floats = 200704 B

  qcnn_circuit_kernel<<<196, 64, 0, stream>>>(images, rp, q);
  qcnn_fc_kernel<<<64, 64, 0, stream>>>(q, fcw, fcb, out);
}

// Round 2
// 19.678 us; speedup vs baseline: 1.8997x; 1.8997x over previous
//
#include <hip/hip_runtime.h>
#include <math.h>

#define PI_F 3.14159265358979323846f

// ---------------------------------------------------------------------------
// Amplitude-per-lane 4-qubit simulator.
// 16 lanes = 1 circuit (one 2x2 patch); lane holds ONE complex amplitude.
// All CNOTs are linear maps over GF(2) on the 4-bit amplitude index, so they
// are folded into a compile-time lane-relabeling: lane l holds a[f(l)], f
// linear. A 1-qubit gate on bit p then needs:
//   partner lane  = l ^ f^{-1}(e_p)        (compile-time shfl_xor mask)
//   row-select    = parity(l & F[p])       (compile-time AND mask)
// All 84 gate masks computed by constexpr GF(2) algebra below.
// Index convention: n = q0*8 + q1*4 + q2*2 + q3  (wire w <-> bit 3-w).
// ---------------------------------------------------------------------------

struct Gates { int xm[84]; int sm[84]; int fin[4]; };

constexpr Gates make_gates() {
  Gates gt{};
  // F[p]: row p of f (bit_p(f(l)) = parity(l & F[p]))
  // H[p]: row p of f^{-1}
  int F[4] = {1, 2, 4, 8};
  int H[4] = {1, 2, 4, 8};
  int ng = 0;
  auto cnot = [&](int c, int t) {
    const int pc = 3 - c, pt = 3 - t;
    F[pt] ^= F[pc];
    for (int p = 0; p < 4; ++p)
      if (H[p] & (1 << pt)) H[p] ^= (1 << pc);
  };
  auto gate = [&](int w) {
    const int p = 3 - w;
    int m = 0;
    for (int q = 0; q < 4; ++q)
      if (H[q] & (1 << p)) m |= 1 << q;   // m = f^{-1}(e_p)
    gt.xm[ng] = m; gt.sm[ng] = F[p]; ++ng;
  };
  for (int step = 0; step < 20; ++step)
    for (int j = 0; j < 4; ++j) {
      gate(j);
      cnot(0, 1); cnot(1, 2); cnot(2, 3); cnot(3, 0);
    }
  // RandomLayers stand-in: rx@3, ry@1, CNOT(0,2), rz@0, rx@2, CNOT(1,3)
  gate(3); gate(1); cnot(0, 2); gate(0); gate(2); cnot(1, 3);
  for (int p = 0; p < 4; ++p) gt.fin[p] = F[p];
  return gt;
}

constexpr Gates GT = make_gates();

// Gate with the Rot symmetry: u00=(WR,WI), u01=(XR,XI), u10=(-XR,XI),
// u11=(WR,-WI). Row select (sel = bit of held index on the gate's wire)
// reduces to two sign flips. Covers Rot, RX (W=(c,0),X=(0,-s)),
// RY (W=(c,0),X=(-s,0)), RZ (W=(c,-s),X=(0,0)).
#define APPLY_GATE(K, WR, WI, XR, XI) do {                                    \
    const float pre_ = __shfl_xor(re, GT.xm[K]);                              \
    const float pim_ = __shfl_xor(im, GT.xm[K]);                              \
    const unsigned sb_ = (unsigned)(__popc(l16 & GT.sm[K]) & 1) << 31;        \
    const float cmi_ = __uint_as_float(__float_as_uint(WI) ^ sb_);            \
    const float cpr_ = __uint_as_float(__float_as_uint(XR) ^ sb_);            \
    const float nre_ = (WR)*re - cmi_*im + cpr_*pre_ - (XI)*pim_;             \
    const float nim_ = (WR)*im + cmi_*re + cpr_*pim_ + (XI)*pre_;             \
    re = nre_; im = nim_;                                                     \
  } while (0)

__global__ __launch_bounds__(256) void qcnn_circuit_kernel(
    const float* __restrict__ images,   // (64,1,28,28)
    const float* __restrict__ rp,       // (4,)
    float* __restrict__ qout)           // (64*196*4,)
{
  const int gtid = blockIdx.x * 256 + threadIdx.x;
  const int c    = gtid >> 4;          // circuit id, 0..12543
  const int l16  = gtid & 15;          // lane within circuit = initial amp idx

  const int b  = c / 196;
  const int pi = c - b * 196;
  const int pj = pi / 14;
  const int pk = pi - pj * 14;

  const float* img = images + b * 784 + (2 * pj) * 28 + 2 * pk;
  float px[4];
  px[0] = img[0]  * PI_F;
  px[1] = img[1]  * PI_F;
  px[2] = img[28] * PI_F;
  px[3] = img[29] * PI_F;

  // 4 distinct Rot matrices (GROUP_IDX period 4); hw sin/cos (err ~1e-7,
  // threshold 7e-2).
  float wr[4], wi[4], xr[4], xi[4];
  {
    const int GIphi[4] = {0, 3, 2, 1};
    const int GIth [4] = {1, 0, 3, 2};
    const int GIom [4] = {2, 1, 0, 3};
#pragma unroll
    for (int g = 0; g < 4; ++g) {
      const float phi = px[GIphi[g]], th = px[GIth[g]], om = px[GIom[g]];
      const float a = 0.5f * (phi + om), d = 0.5f * (phi - om), h = 0.5f * th;
      const float sa = __sinf(a), ca = __cosf(a);
      const float sd = __sinf(d), cd = __cosf(d);
      const float st = __sinf(h), ct = __cosf(h);
      wr[g] =  ca * ct;  wi[g] = -sa * ct;   // u00
      xr[g] = -cd * st;  xi[g] = -sd * st;   // u01
    }
  }

  // |0000>: lane l holds a[f(l)] = a[l] initially (f = identity).
  float re = (l16 == 0) ? 1.f : 0.f;
  float im = 0.f;

  // 80 Rot gates; CNOTs are free (folded into the masks).
#pragma unroll
  for (int step = 0; step < 20; ++step) {
    const int g = step & 3;
#pragma unroll
    for (int j = 0; j < 4; ++j) {
      const int k = step * 4 + j;
      APPLY_GATE(k, wr[g], wi[g], xr[g], xi[g]);
    }
  }

  // Final 4 gates (masks 80..83): RX(rp0)@w3, RY(rp1)@w1, RZ(rp2)@w0, RX(rp3)@w2
  {
    const float s0 = __sinf(0.5f * rp[0]), c0 = __cosf(0.5f * rp[0]);
    APPLY_GATE(80, c0, 0.f, 0.f, -s0);                   // RX
    const float s1 = __sinf(0.5f * rp[1]), c1 = __cosf(0.5f * rp[1]);
    APPLY_GATE(81, c1, 0.f, -s1, 0.f);                   // RY
    const float s2 = __sinf(0.5f * rp[2]), c2 = __cosf(0.5f * rp[2]);
    APPLY_GATE(82, c2, -s2, 0.f, 0.f);                   // RZ (diagonal)
    const float s3 = __sinf(0.5f * rp[3]), c3 = __cosf(0.5f * rp[3]);
    APPLY_GATE(83, c3, 0.f, 0.f, -s3);                   // RX
  }

  // PauliZ expvals: lane holds a[f(l)]; sign for wire j = parity(l & fin[3-j]).
  const float pr = re * re + im * im;
  float e0 = __uint_as_float(__float_as_uint(pr) ^ ((unsigned)(__popc(l16 & GT.fin[3]) & 1) << 31));
  float e1 = __uint_as_float(__float_as_uint(pr) ^ ((unsigned)(__popc(l16 & GT.fin[2]) & 1) << 31));
  float e2 = __uint_as_float(__float_as_uint(pr) ^ ((unsigned)(__popc(l16 & GT.fin[1]) & 1) << 31));
  float e3 = __uint_as_float(__float_as_uint(pr) ^ ((unsigned)(__popc(l16 & GT.fin[0]) & 1) << 31));
#pragma unroll
  for (int s = 1; s < 16; s <<= 1) {
    e0 += __shfl_xor(e0, s);
    e1 += __shfl_xor(e1, s);
    e2 += __shfl_xor(e2, s);
    e3 += __shfl_xor(e3, s);
  }
  float v = e0;
  v = (l16 == 1) ? e1 : v;
  v = (l16 == 2) ? e2 : v;
  v = (l16 == 3) ? e3 : v;
  if (l16 < 4) qout[c * 4 + l16] = v;
}

// ---------------------------------------------------------------------------
// FC (10x784) + log_softmax. One wave per image, float4 loads.
// ---------------------------------------------------------------------------
__global__ __launch_bounds__(64) void qcnn_fc_kernel(
    const float* __restrict__ q,     // (64,784)
    const float* __restrict__ fcw,   // (10,784)
    const float* __restrict__ fcb,   // (10,)
    float* __restrict__ out)         // (64,10)
{
  const int b    = blockIdx.x;
  const int lane = threadIdx.x;
  const float4* q4 = reinterpret_cast<const float4*>(q + b * 784);
  const float4* w4 = reinterpret_cast<const float4*>(fcw);

  float acc[10];
#pragma unroll
  for (int o = 0; o < 10; ++o) acc[o] = 0.f;

  for (int i = lane; i < 196; i += 64) {
    const float4 qv = q4[i];
#pragma unroll
    for (int o = 0; o < 10; ++o) {
      const float4 wv = w4[o * 196 + i];
      acc[o] += qv.x * wv.x + qv.y * wv.y + qv.z * wv.z + qv.w * wv.w;
    }
  }

#pragma unroll
  for (int o = 0; o < 10; ++o) {
    for (int off = 32; off > 0; off >>= 1)
      acc[o] += __shfl_down(acc[o], off);
  }

  if (lane == 0) {
    float logits[10];
    float mx = -1e30f;
#pragma unroll
    for (int o = 0; o < 10; ++o) {
      logits[o] = acc[o] + fcb[o];
      mx = fmaxf(mx, logits[o]);
    }
    float se = 0.f;
#pragma unroll
    for (int o = 0; o < 10; ++o) se += __expf(logits[o] - mx);
    const float lse = mx + __logf(se);
#pragma unroll
    for (int o = 0; o < 10; ++o) out[b * 10 + o] = logits[o] - lse;
  }
}

// ---------------------------------------------------------------------------

extern "C" void kernel_launch(void* const* d_in, const int* in_sizes, int n_in,
                              void* d_out, int out_size, void* d_ws, size_t ws_size,
                              hipStream_t stream) {
  const float* images = (const float*)d_in[0];   // 64*1*28*28
  const float* rp     = (const float*)d_in[1];   // 4
  const float* fcw    = (const float*)d_in[2];   // 10*784
  const float* fcb    = (const float*)d_in[3];   // 10
  float* out = (float*)d_out;                    // 64*10
  float* q   = (float*)d_ws;                     // 64*196*4 floats

  // 12544 circuits x 16 lanes = 200704 threads = 784 blocks x 256
  qcnn_circuit_kernel<<<784, 256, 0, stream>>>(images, rp, q);
  qcnn_fc_kernel<<<64, 64, 0, stream>>>(q, fcw, fcb, out);
}